// Round 1
// baseline (1099.735 us; speedup 1.0000x reference)
//
#include <hip/hip_runtime.h>
#include <cstdint>
#include <cstddef>

#define BN_EPS 1e-5f

// ---------------- graph preprocessing ----------------

__global__ void count_deg_kernel(const int* __restrict__ dst, int* __restrict__ cnt, int e) {
    int i = blockIdx.x * 256 + threadIdx.x;
    if (i < e) atomicAdd(&cnt[dst[i]], 1);
}

__global__ void dinv_kernel(const int* __restrict__ cnt, float* __restrict__ dinv, int n) {
    int i = blockIdx.x * 256 + threadIdx.x;
    if (i < n) dinv[i] = rsqrtf((float)(cnt[i] + 1));   // +1 self-loop; always > 0
}

// single-block exclusive scan over cnt -> rowptr (and cursor copy)
__global__ void scan_kernel(const int* __restrict__ cnt, int* __restrict__ rowptr,
                            int* __restrict__ cursor, int n) {
    __shared__ int bs[1024];
    int t = threadIdx.x;
    int chunk = (n + 1023) >> 10;
    int lo = t * chunk;
    int hi = lo + chunk; if (hi > n) hi = n;
    int s = 0;
    for (int i = lo; i < hi; i++) s += cnt[i];
    bs[t] = s;
    __syncthreads();
    for (int off = 1; off < 1024; off <<= 1) {
        int v = (t >= off) ? bs[t - off] : 0;
        __syncthreads();
        bs[t] += v;
        __syncthreads();
    }
    int run = (t == 0) ? 0 : bs[t - 1];
    for (int i = lo; i < hi; i++) {
        rowptr[i] = run;
        cursor[i] = run;
        run += cnt[i];
    }
}

__global__ void fill_csr_kernel(const int* __restrict__ src, const int* __restrict__ dst,
                                int* __restrict__ cursor, int* __restrict__ esrc,
                                float* __restrict__ enorm, const float* __restrict__ dinv, int e) {
    int i = blockIdx.x * 256 + threadIdx.x;
    if (i >= e) return;
    int s = src[i], d = dst[i];
    int pos = atomicAdd(&cursor[d], 1);
    esrc[pos] = s;
    enorm[pos] = dinv[s] * dinv[d];
}

// ---------------- GEMM: Y[n,OUTC] = act(X[n,128]) @ W[128,OUTC] ----------------
// act = identity, or BN(scale,shift)+ReLU fused on the input while staging.
// 64-row tile per block; X^T in LDS (stride 68 -> conflict-free b128 reads);
// W streamed from global (hot in L1/L2 across all blocks).

template <int OUTC>
__global__ __launch_bounds__(256) void gemm_kernel(const float* __restrict__ X,
                                                   const float* __restrict__ W,
                                                   const float* __restrict__ scale,
                                                   const float* __restrict__ shift,
                                                   float* __restrict__ Y, int n) {
    constexpr int RPT = (OUTC == 128) ? 8 : 4;  // rows per thread
    constexpr int CG  = OUTC / 4;               // col groups (float4 each)
    __shared__ float lXT[128 * 68];             // [k][row], 34.8 KB
    const int t = threadIdx.x;
    const int base = blockIdx.x * 64;
    const bool bn = (scale != nullptr);

    // stage X^T (64 rows x 128 k) with optional BN+ReLU
#pragma unroll
    for (int i = 0; i < 8; i++) {
        int id = i * 256 + t;
        int k  = id & 127;
        int r4 = id >> 7;  // 0..15
        float sc = 1.0f, sh = 0.0f;
        if (bn) { sc = scale[k]; sh = shift[k]; }
        float v[4];
#pragma unroll
        for (int j = 0; j < 4; j++) {
            int r = base + r4 * 4 + j;
            float xv = 0.0f;
            if (r < n) xv = X[(size_t)r * 128 + k];
            if (bn) xv = fmaxf(fmaf(xv, sc, sh), 0.0f);
            v[j] = xv;
        }
        float4 vv; vv.x = v[0]; vv.y = v[1]; vv.z = v[2]; vv.w = v[3];
        *(float4*)&lXT[k * 68 + r4 * 4] = vv;
    }
    __syncthreads();

    const int cg = t % CG;
    const int rg = t / CG;
    float acc[RPT][4];
#pragma unroll
    for (int i = 0; i < RPT; i++)
#pragma unroll
        for (int j = 0; j < 4; j++) acc[i][j] = 0.0f;

#pragma unroll 4
    for (int k = 0; k < 128; k++) {
        float4 b = *(const float4*)&W[k * OUTC + cg * 4];
        float a[RPT];
        *(float4*)&a[0] = *(const float4*)&lXT[k * 68 + rg * RPT];
        if constexpr (RPT == 8)
            *(float4*)&a[4] = *(const float4*)&lXT[k * 68 + rg * RPT + 4];
#pragma unroll
        for (int i = 0; i < RPT; i++) {
            acc[i][0] = fmaf(a[i], b.x, acc[i][0]);
            acc[i][1] = fmaf(a[i], b.y, acc[i][1]);
            acc[i][2] = fmaf(a[i], b.z, acc[i][2]);
            acc[i][3] = fmaf(a[i], b.w, acc[i][3]);
        }
    }

#pragma unroll
    for (int i = 0; i < RPT; i++) {
        int r = base + rg * RPT + i;
        if (r < n) {
            float4 o; o.x = acc[i][0]; o.y = acc[i][1]; o.z = acc[i][2]; o.w = acc[i][3];
            *(float4*)&Y[(size_t)r * OUTC + cg * 4] = o;
        }
    }
}

// ---------------- aggregation: out[i] = sum_{e:dst=i} norm_e * xw[src_e] + dinv[i]^2 * xw[i] + bias ----------------
// one wave per node; float2 (COLS=128) or float (COLS=64) per lane.

template <int COLS>
__global__ __launch_bounds__(256) void agg_kernel(const float* __restrict__ xw,
                                                  const int* __restrict__ rowptr,
                                                  const int* __restrict__ cnt,
                                                  const int* __restrict__ esrc,
                                                  const float* __restrict__ enorm,
                                                  const float* __restrict__ dinv,
                                                  const float* __restrict__ bias,
                                                  float* __restrict__ out, int n) {
    int gid = blockIdx.x * 256 + threadIdx.x;
    int node = gid >> 6;
    int lane = gid & 63;
    if (node >= n) return;
    float di = dinv[node];
    float sw = di * di;
    int beg = rowptr[node];
    int end = beg + cnt[node];

    if constexpr (COLS == 128) {
        float2 a = ((const float2*)(xw + (size_t)node * 128))[lane];
        float ax = sw * a.x, ay = sw * a.y;
        int s_nxt = 0; float w_nxt = 0.0f;
        if (beg < end) { s_nxt = esrc[beg]; w_nxt = enorm[beg]; }
        for (int e = beg; e < end; e++) {
            int s = s_nxt; float w = w_nxt;
            if (e + 1 < end) { s_nxt = esrc[e + 1]; w_nxt = enorm[e + 1]; }
            float2 v = ((const float2*)(xw + (size_t)s * 128))[lane];
            ax = fmaf(w, v.x, ax);
            ay = fmaf(w, v.y, ay);
        }
        float2 b = ((const float2*)bias)[lane];
        float2 o; o.x = ax + b.x; o.y = ay + b.y;
        ((float2*)(out + (size_t)node * 128))[lane] = o;
    } else {
        float acc = sw * xw[(size_t)node * 64 + lane];
        int s_nxt = 0; float w_nxt = 0.0f;
        if (beg < end) { s_nxt = esrc[beg]; w_nxt = enorm[beg]; }
        for (int e = beg; e < end; e++) {
            int s = s_nxt; float w = w_nxt;
            if (e + 1 < end) { s_nxt = esrc[e + 1]; w_nxt = enorm[e + 1]; }
            acc = fmaf(w, xw[(size_t)s * 64 + lane], acc);
        }
        out[(size_t)node * 64 + lane] = acc + bias[lane];
    }
}

// ---------------- BatchNorm (training-mode, biased var) ----------------

__global__ void bn_stats_kernel(const float* __restrict__ h, float* __restrict__ sums, int n) {
    int c = threadIdx.x & 127;
    int half = threadIdx.x >> 7;
    float s = 0.0f, q = 0.0f;
    for (int r = blockIdx.x * 2 + half; r < n; r += gridDim.x * 2) {
        float v = h[(size_t)r * 128 + c];
        s += v;
        q = fmaf(v, v, q);
    }
    __shared__ float ls[256], lq[256];
    ls[threadIdx.x] = s; lq[threadIdx.x] = q;
    __syncthreads();
    if (half == 0) {
        s += ls[c + 128];
        q += lq[c + 128];
        atomicAdd(&sums[c], s);
        atomicAdd(&sums[128 + c], q);
    }
}

__global__ void bn_finalize_kernel(const float* __restrict__ sums, const float* __restrict__ g,
                                   const float* __restrict__ be, float* __restrict__ scale,
                                   float* __restrict__ shift, int n) {
    int c = threadIdx.x;  // 128 threads
    float inv_n = 1.0f / (float)n;
    float mean = sums[c] * inv_n;
    float var = sums[128 + c] * inv_n - mean * mean;
    float rstd = rsqrtf(var + BN_EPS);
    float sc = rstd * g[c];
    scale[c] = sc;
    shift[c] = be[c] - mean * sc;
}

// ---------------- launch ----------------

extern "C" void kernel_launch(void* const* d_in, const int* in_sizes, int n_in,
                              void* d_out, int out_size, void* d_ws, size_t ws_size,
                              hipStream_t stream) {
    const float* x   = (const float*)d_in[0];
    const int*   ei  = (const int*)d_in[1];
    const float* W1  = (const float*)d_in[2];
    const float* b1  = (const float*)d_in[3];
    const float* g1  = (const float*)d_in[4];
    const float* be1 = (const float*)d_in[5];
    const float* W2  = (const float*)d_in[6];
    const float* b2  = (const float*)d_in[7];
    const float* g2  = (const float*)d_in[8];
    const float* be2 = (const float*)d_in[9];
    const float* W3  = (const float*)d_in[10];
    const float* b3  = (const float*)d_in[11];

    const int n = in_sizes[0] / 128;
    const int E = in_sizes[1] / 2;
    const int* srcv = ei;
    const int* dstv = ei + E;

    char* p = (char*)d_ws;
    auto carve = [&](size_t bytes) -> char* {
        char* q = p;
        p += (bytes + 255) & ~(size_t)255;
        return q;
    };
    int*   cnt    = (int*)carve((size_t)n * 4);
    int*   rowptr = (int*)carve((size_t)n * 4);
    int*   cursor = (int*)carve((size_t)n * 4);
    float* dinv   = (float*)carve((size_t)n * 4);
    int*   esrc   = (int*)carve((size_t)E * 4);
    float* enorm  = (float*)carve((size_t)E * 4);
    float* sums   = (float*)carve(512 * 4);   // [sum1|sq1|sum2|sq2]
    float* bnsc   = (float*)carve(512 * 4);   // [scale1|shift1|scale2|shift2]
    float* bufA   = (float*)carve((size_t)n * 128 * 4);
    float* bufB   = (float*)carve((size_t)n * 128 * 4);

    hipMemsetAsync(cnt, 0, (size_t)n * 4, stream);
    hipMemsetAsync(sums, 0, 512 * 4, stream);

    int eb = (E + 255) / 256;
    int nb = (n + 255) / 256;
    count_deg_kernel<<<eb, 256, 0, stream>>>(dstv, cnt, E);
    dinv_kernel<<<nb, 256, 0, stream>>>(cnt, dinv, n);
    scan_kernel<<<1, 1024, 0, stream>>>(cnt, rowptr, cursor, n);
    fill_csr_kernel<<<eb, 256, 0, stream>>>(srcv, dstv, cursor, esrc, enorm, dinv, E);

    int gb = (n + 63) / 64;
    int ab = (n + 3) / 4;

    // layer 1: gcn(x, W1) + b1
    gemm_kernel<128><<<gb, 256, 0, stream>>>(x, W1, nullptr, nullptr, bufA, n);
    agg_kernel<128><<<ab, 256, 0, stream>>>(bufA, rowptr, cnt, esrc, enorm, dinv, b1, bufB, n);
    bn_stats_kernel<<<512, 256, 0, stream>>>(bufB, sums, n);
    bn_finalize_kernel<<<1, 128, 0, stream>>>(sums, g1, be1, bnsc, bnsc + 128, n);

    // layer 2: gcn(relu(bn1(h)), W2) + b2   (bn1+relu fused into gemm staging)
    gemm_kernel<128><<<gb, 256, 0, stream>>>(bufB, W2, bnsc, bnsc + 128, bufA, n);
    agg_kernel<128><<<ab, 256, 0, stream>>>(bufA, rowptr, cnt, esrc, enorm, dinv, b2, bufB, n);
    bn_stats_kernel<<<512, 256, 0, stream>>>(bufB, sums + 256, n);
    bn_finalize_kernel<<<1, 128, 0, stream>>>(sums + 256, g2, be2, bnsc + 256, bnsc + 384, n);

    // layer 3: gcn(relu(bn2(h)), W3) + b3  -> d_out
    gemm_kernel<64><<<gb, 256, 0, stream>>>(bufB, W3, bnsc + 256, bnsc + 384, bufA, n);
    agg_kernel<64><<<ab, 256, 0, stream>>>(bufA, rowptr, cnt, esrc, enorm, dinv, b3, (float*)d_out, n);
}

// Round 2
// 879.320 us; speedup vs baseline: 1.2507x; 1.2507x over previous
//
#include <hip/hip_runtime.h>
#include <cstdint>
#include <cstddef>

#define BN_EPS 1e-5f

// ---------------- graph preprocessing ----------------

__global__ void count_deg_kernel(const int* __restrict__ dst, int* __restrict__ cnt, int e) {
    int i = blockIdx.x * 256 + threadIdx.x;
    if (i < e) atomicAdd(&cnt[dst[i]], 1);
}

__global__ void dinv_kernel(const int* __restrict__ cnt, float* __restrict__ dinv, int n) {
    int i = blockIdx.x * 256 + threadIdx.x;
    if (i < n) dinv[i] = rsqrtf((float)(cnt[i] + 1));   // +1 self-loop; always > 0
}

// ---- 3-phase device-wide exclusive scan: 1024 elements/block, 256 thr ----

__global__ void blocksum_kernel(const int* __restrict__ cnt, int* __restrict__ bsum, int n) {
    int t = threadIdx.x;
    int base = blockIdx.x * 1024 + t * 4;
    int s = 0;
    if (base + 3 < n) {
        int4 v = *(const int4*)&cnt[base];
        s = v.x + v.y + v.z + v.w;
    } else {
        for (int j = 0; j < 4; j++) if (base + j < n) s += cnt[base + j];
    }
    __shared__ int ls[256];
    ls[t] = s;
    __syncthreads();
    for (int off = 128; off > 0; off >>= 1) {
        if (t < off) ls[t] += ls[t + off];
        __syncthreads();
    }
    if (t == 0) bsum[blockIdx.x] = ls[0];
}

// single block, nb <= 256: exclusive scan of bsum in place
__global__ void scan_bsum_kernel(int* __restrict__ bsum, int nb) {
    int t = threadIdx.x;
    __shared__ int ls[256];
    int v = (t < nb) ? bsum[t] : 0;
    ls[t] = v;
    __syncthreads();
    for (int off = 1; off < 256; off <<= 1) {
        int p = (t >= off) ? ls[t - off] : 0;
        __syncthreads();
        ls[t] += p;
        __syncthreads();
    }
    if (t < nb) bsum[t] = ls[t] - v;   // inclusive -> exclusive
}

__global__ void scan_write_kernel(const int* __restrict__ cnt, const int* __restrict__ bsum,
                                  int* __restrict__ rowptr, int* __restrict__ cursor, int n) {
    int t = threadIdx.x;
    int base = blockIdx.x * 1024 + t * 4;
    int v[4];
    int s = 0;
    if (base + 3 < n) {
        int4 q = *(const int4*)&cnt[base];
        v[0] = q.x; v[1] = q.y; v[2] = q.z; v[3] = q.w;
        s = q.x + q.y + q.z + q.w;
    } else {
        for (int j = 0; j < 4; j++) { v[j] = (base + j < n) ? cnt[base + j] : 0; s += v[j]; }
    }
    __shared__ int ls[256];
    ls[t] = s;
    __syncthreads();
    for (int off = 1; off < 256; off <<= 1) {
        int p = (t >= off) ? ls[t - off] : 0;
        __syncthreads();
        ls[t] += p;
        __syncthreads();
    }
    int run = bsum[blockIdx.x] + ls[t] - s;   // exclusive offset for this thread
    if (base + 3 < n) {
        int4 r; r.x = run; r.y = run + v[0]; r.z = run + v[0] + v[1]; r.w = run + v[0] + v[1] + v[2];
        *(int4*)&rowptr[base] = r;
        *(int4*)&cursor[base] = r;
    } else {
        for (int j = 0; j < 4; j++) {
            if (base + j < n) { rowptr[base + j] = run; cursor[base + j] = run; }
            run += v[j];
        }
    }
}

__global__ void fill_csr_kernel(const int* __restrict__ src, const int* __restrict__ dst,
                                int* __restrict__ cursor, int* __restrict__ esrc,
                                float* __restrict__ enorm, const float* __restrict__ dinv, int e) {
    int i = blockIdx.x * 256 + threadIdx.x;
    if (i >= e) return;
    int s = src[i], d = dst[i];
    int pos = atomicAdd(&cursor[d], 1);
    esrc[pos] = s;
    enorm[pos] = dinv[s] * dinv[d];
}

// ---------------- GEMM: Y[n,OUTC] = act(X[n,128]) @ W[128,OUTC] ----------------
// act = identity, or BN(scale,shift)+ReLU fused on the input while staging.
// 64-row tile per block; X^T in LDS (stride 68 -> conflict-free b128 reads);
// W streamed from global (hot in L1/L2 across all blocks).

template <int OUTC>
__global__ __launch_bounds__(256) void gemm_kernel(const float* __restrict__ X,
                                                   const float* __restrict__ W,
                                                   const float* __restrict__ scale,
                                                   const float* __restrict__ shift,
                                                   float* __restrict__ Y, int n) {
    constexpr int RPT = (OUTC == 128) ? 8 : 4;  // rows per thread
    constexpr int CG  = OUTC / 4;               // col groups (float4 each)
    __shared__ float lXT[128 * 68];             // [k][row], 34.8 KB
    const int t = threadIdx.x;
    const int base = blockIdx.x * 64;
    const bool bn = (scale != nullptr);

    // stage X^T (64 rows x 128 k) with optional BN+ReLU
#pragma unroll
    for (int i = 0; i < 8; i++) {
        int id = i * 256 + t;
        int k  = id & 127;
        int r4 = id >> 7;  // 0..15
        float sc = 1.0f, sh = 0.0f;
        if (bn) { sc = scale[k]; sh = shift[k]; }
        float v[4];
#pragma unroll
        for (int j = 0; j < 4; j++) {
            int r = base + r4 * 4 + j;
            float xv = 0.0f;
            if (r < n) xv = X[(size_t)r * 128 + k];
            if (bn) xv = fmaxf(fmaf(xv, sc, sh), 0.0f);
            v[j] = xv;
        }
        float4 vv; vv.x = v[0]; vv.y = v[1]; vv.z = v[2]; vv.w = v[3];
        *(float4*)&lXT[k * 68 + r4 * 4] = vv;
    }
    __syncthreads();

    const int cg = t % CG;
    const int rg = t / CG;
    float acc[RPT][4];
#pragma unroll
    for (int i = 0; i < RPT; i++)
#pragma unroll
        for (int j = 0; j < 4; j++) acc[i][j] = 0.0f;

#pragma unroll 4
    for (int k = 0; k < 128; k++) {
        float4 b = *(const float4*)&W[k * OUTC + cg * 4];
        float a[RPT];
        *(float4*)&a[0] = *(const float4*)&lXT[k * 68 + rg * RPT];
        if constexpr (RPT == 8)
            *(float4*)&a[4] = *(const float4*)&lXT[k * 68 + rg * RPT + 4];
#pragma unroll
        for (int i = 0; i < RPT; i++) {
            acc[i][0] = fmaf(a[i], b.x, acc[i][0]);
            acc[i][1] = fmaf(a[i], b.y, acc[i][1]);
            acc[i][2] = fmaf(a[i], b.z, acc[i][2]);
            acc[i][3] = fmaf(a[i], b.w, acc[i][3]);
        }
    }

#pragma unroll
    for (int i = 0; i < RPT; i++) {
        int r = base + rg * RPT + i;
        if (r < n) {
            float4 o; o.x = acc[i][0]; o.y = acc[i][1]; o.z = acc[i][2]; o.w = acc[i][3];
            *(float4*)&Y[(size_t)r * OUTC + cg * 4] = o;
        }
    }
}

// ---------------- aggregation: out[i] = sum_{e:dst=i} norm_e * xw[src_e] + dinv[i]^2 * xw[i] + bias ----------------
// one wave per node; float2 (COLS=128) or float (COLS=64) per lane.

template <int COLS>
__global__ __launch_bounds__(256) void agg_kernel(const float* __restrict__ xw,
                                                  const int* __restrict__ rowptr,
                                                  const int* __restrict__ cnt,
                                                  const int* __restrict__ esrc,
                                                  const float* __restrict__ enorm,
                                                  const float* __restrict__ dinv,
                                                  const float* __restrict__ bias,
                                                  float* __restrict__ out, int n) {
    int gid = blockIdx.x * 256 + threadIdx.x;
    int node = gid >> 6;
    int lane = gid & 63;
    if (node >= n) return;
    float di = dinv[node];
    float sw = di * di;
    int beg = rowptr[node];
    int end = beg + cnt[node];

    if constexpr (COLS == 128) {
        float2 a = ((const float2*)(xw + (size_t)node * 128))[lane];
        float ax = sw * a.x, ay = sw * a.y;
        int s_nxt = 0; float w_nxt = 0.0f;
        if (beg < end) { s_nxt = esrc[beg]; w_nxt = enorm[beg]; }
        for (int e = beg; e < end; e++) {
            int s = s_nxt; float w = w_nxt;
            if (e + 1 < end) { s_nxt = esrc[e + 1]; w_nxt = enorm[e + 1]; }
            float2 v = ((const float2*)(xw + (size_t)s * 128))[lane];
            ax = fmaf(w, v.x, ax);
            ay = fmaf(w, v.y, ay);
        }
        float2 b = ((const float2*)bias)[lane];
        float2 o; o.x = ax + b.x; o.y = ay + b.y;
        ((float2*)(out + (size_t)node * 128))[lane] = o;
    } else {
        float acc = sw * xw[(size_t)node * 64 + lane];
        int s_nxt = 0; float w_nxt = 0.0f;
        if (beg < end) { s_nxt = esrc[beg]; w_nxt = enorm[beg]; }
        for (int e = beg; e < end; e++) {
            int s = s_nxt; float w = w_nxt;
            if (e + 1 < end) { s_nxt = esrc[e + 1]; w_nxt = enorm[e + 1]; }
            acc = fmaf(w, xw[(size_t)s * 64 + lane], acc);
        }
        out[(size_t)node * 64 + lane] = acc + bias[lane];
    }
}

// ---------------- BatchNorm (training-mode, biased var) ----------------

__global__ void bn_stats_kernel(const float* __restrict__ h, float* __restrict__ sums, int n) {
    int c = threadIdx.x & 127;
    int half = threadIdx.x >> 7;
    float s = 0.0f, q = 0.0f;
    for (int r = blockIdx.x * 2 + half; r < n; r += gridDim.x * 2) {
        float v = h[(size_t)r * 128 + c];
        s += v;
        q = fmaf(v, v, q);
    }
    __shared__ float ls[256], lq[256];
    ls[threadIdx.x] = s; lq[threadIdx.x] = q;
    __syncthreads();
    if (half == 0) {
        s += ls[c + 128];
        q += lq[c + 128];
        atomicAdd(&sums[c], s);
        atomicAdd(&sums[128 + c], q);
    }
}

__global__ void bn_finalize_kernel(const float* __restrict__ sums, const float* __restrict__ g,
                                   const float* __restrict__ be, float* __restrict__ scale,
                                   float* __restrict__ shift, int n) {
    int c = threadIdx.x;  // 128 threads
    float inv_n = 1.0f / (float)n;
    float mean = sums[c] * inv_n;
    float var = sums[128 + c] * inv_n - mean * mean;
    float rstd = rsqrtf(var + BN_EPS);
    float sc = rstd * g[c];
    scale[c] = sc;
    shift[c] = be[c] - mean * sc;
}

// ---------------- launch ----------------

extern "C" void kernel_launch(void* const* d_in, const int* in_sizes, int n_in,
                              void* d_out, int out_size, void* d_ws, size_t ws_size,
                              hipStream_t stream) {
    const float* x   = (const float*)d_in[0];
    const int*   ei  = (const int*)d_in[1];
    const float* W1  = (const float*)d_in[2];
    const float* b1  = (const float*)d_in[3];
    const float* g1  = (const float*)d_in[4];
    const float* be1 = (const float*)d_in[5];
    const float* W2  = (const float*)d_in[6];
    const float* b2  = (const float*)d_in[7];
    const float* g2  = (const float*)d_in[8];
    const float* be2 = (const float*)d_in[9];
    const float* W3  = (const float*)d_in[10];
    const float* b3  = (const float*)d_in[11];

    const int n = in_sizes[0] / 128;
    const int E = in_sizes[1] / 2;
    const int* srcv = ei;
    const int* dstv = ei + E;

    char* p = (char*)d_ws;
    auto carve = [&](size_t bytes) -> char* {
        char* q = p;
        p += (bytes + 255) & ~(size_t)255;
        return q;
    };
    int*   cnt    = (int*)carve((size_t)n * 4);
    int*   rowptr = (int*)carve((size_t)n * 4);
    int*   cursor = (int*)carve((size_t)n * 4);
    float* dinv   = (float*)carve((size_t)n * 4);
    int*   esrc   = (int*)carve((size_t)E * 4);
    float* enorm  = (float*)carve((size_t)E * 4);
    float* sums   = (float*)carve(512 * 4);   // [sum1|sq1|sum2|sq2]
    float* bnsc   = (float*)carve(512 * 4);   // [scale1|shift1|scale2|shift2]
    int*   bsum   = (int*)carve(1024 * 4);
    float* bufA   = (float*)carve((size_t)n * 128 * 4);
    float* bufB   = (float*)carve((size_t)n * 128 * 4);

    hipMemsetAsync(cnt, 0, (size_t)n * 4, stream);
    hipMemsetAsync(sums, 0, 512 * 4, stream);

    int eb = (E + 255) / 256;
    int nb = (n + 255) / 256;
    int sb = (n + 1023) / 1024;   // scan blocks (1024 elems per block); must be <= 256
    count_deg_kernel<<<eb, 256, 0, stream>>>(dstv, cnt, E);
    dinv_kernel<<<nb, 256, 0, stream>>>(cnt, dinv, n);
    blocksum_kernel<<<sb, 256, 0, stream>>>(cnt, bsum, n);
    scan_bsum_kernel<<<1, 256, 0, stream>>>(bsum, sb);
    scan_write_kernel<<<sb, 256, 0, stream>>>(cnt, bsum, rowptr, cursor, n);
    fill_csr_kernel<<<eb, 256, 0, stream>>>(srcv, dstv, cursor, esrc, enorm, dinv, E);

    int gb = (n + 63) / 64;
    int ab = (n + 3) / 4;

    // layer 1: gcn(x, W1) + b1
    gemm_kernel<128><<<gb, 256, 0, stream>>>(x, W1, nullptr, nullptr, bufA, n);
    agg_kernel<128><<<ab, 256, 0, stream>>>(bufA, rowptr, cnt, esrc, enorm, dinv, b1, bufB, n);
    bn_stats_kernel<<<512, 256, 0, stream>>>(bufB, sums, n);
    bn_finalize_kernel<<<1, 128, 0, stream>>>(sums, g1, be1, bnsc, bnsc + 128, n);

    // layer 2: gcn(relu(bn1(h)), W2) + b2   (bn1+relu fused into gemm staging)
    gemm_kernel<128><<<gb, 256, 0, stream>>>(bufB, W2, bnsc, bnsc + 128, bufA, n);
    agg_kernel<128><<<ab, 256, 0, stream>>>(bufA, rowptr, cnt, esrc, enorm, dinv, b2, bufB, n);
    bn_stats_kernel<<<512, 256, 0, stream>>>(bufB, sums + 256, n);
    bn_finalize_kernel<<<1, 128, 0, stream>>>(sums + 256, g2, be2, bnsc + 256, bnsc + 384, n);

    // layer 3: gcn(relu(bn2(h)), W3) + b3  -> d_out
    gemm_kernel<64><<<gb, 256, 0, stream>>>(bufB, W3, bnsc + 256, bnsc + 384, bufA, n);
    agg_kernel<64><<<ab, 256, 0, stream>>>(bufA, rowptr, cnt, esrc, enorm, dinv, b3, (float*)d_out, n);
}

// Round 3
// 846.564 us; speedup vs baseline: 1.2991x; 1.0387x over previous
//
#include <hip/hip_runtime.h>
#include <cstdint>
#include <cstddef>

#define BN_EPS 1e-5f

// ---------------- graph preprocessing ----------------

__global__ void count_deg_kernel(const int* __restrict__ dst, int* __restrict__ cnt, int e) {
    int i = blockIdx.x * 256 + threadIdx.x;
    if (i < e) atomicAdd(&cnt[dst[i]], 1);
}

__global__ void dinv_kernel(const int* __restrict__ cnt, float* __restrict__ dinv, int n) {
    int i = blockIdx.x * 256 + threadIdx.x;
    if (i < n) dinv[i] = rsqrtf((float)(cnt[i] + 1));   // +1 self-loop; always > 0
}

// ---- 3-phase device-wide exclusive scan: 1024 elements/block, 256 thr ----

__global__ void blocksum_kernel(const int* __restrict__ cnt, int* __restrict__ bsum, int n) {
    int t = threadIdx.x;
    int base = blockIdx.x * 1024 + t * 4;
    int s = 0;
    if (base + 3 < n) {
        int4 v = *(const int4*)&cnt[base];
        s = v.x + v.y + v.z + v.w;
    } else {
        for (int j = 0; j < 4; j++) if (base + j < n) s += cnt[base + j];
    }
    __shared__ int ls[256];
    ls[t] = s;
    __syncthreads();
    for (int off = 128; off > 0; off >>= 1) {
        if (t < off) ls[t] += ls[t + off];
        __syncthreads();
    }
    if (t == 0) bsum[blockIdx.x] = ls[0];
}

// single block, nb <= 256: exclusive scan of bsum in place
__global__ void scan_bsum_kernel(int* __restrict__ bsum, int nb) {
    int t = threadIdx.x;
    __shared__ int ls[256];
    int v = (t < nb) ? bsum[t] : 0;
    ls[t] = v;
    __syncthreads();
    for (int off = 1; off < 256; off <<= 1) {
        int p = (t >= off) ? ls[t - off] : 0;
        __syncthreads();
        ls[t] += p;
        __syncthreads();
    }
    if (t < nb) bsum[t] = ls[t] - v;   // inclusive -> exclusive
}

__global__ void scan_write_kernel(const int* __restrict__ cnt, const int* __restrict__ bsum,
                                  int* __restrict__ rowptr, int* __restrict__ cursor, int n) {
    int t = threadIdx.x;
    int base = blockIdx.x * 1024 + t * 4;
    int v[4];
    int s = 0;
    if (base + 3 < n) {
        int4 q = *(const int4*)&cnt[base];
        v[0] = q.x; v[1] = q.y; v[2] = q.z; v[3] = q.w;
        s = q.x + q.y + q.z + q.w;
    } else {
        for (int j = 0; j < 4; j++) { v[j] = (base + j < n) ? cnt[base + j] : 0; s += v[j]; }
    }
    __shared__ int ls[256];
    ls[t] = s;
    __syncthreads();
    for (int off = 1; off < 256; off <<= 1) {
        int p = (t >= off) ? ls[t - off] : 0;
        __syncthreads();
        ls[t] += p;
        __syncthreads();
    }
    int run = bsum[blockIdx.x] + ls[t] - s;   // exclusive offset for this thread
    if (base + 3 < n) {
        int4 r; r.x = run; r.y = run + v[0]; r.z = run + v[0] + v[1]; r.w = run + v[0] + v[1] + v[2];
        *(int4*)&rowptr[base] = r;
        *(int4*)&cursor[base] = r;
    } else {
        for (int j = 0; j < 4; j++) {
            if (base + j < n) { rowptr[base + j] = run; cursor[base + j] = run; }
            run += v[j];
        }
    }
}

// CSR fill: ONLY the src index is scattered (4B/edge). norm is recomputed in agg
// from dinv[src]*dinv[dst] -- halves the scattered write streams vs (esrc, enorm).
__global__ void fill_csr_kernel(const int* __restrict__ src, const int* __restrict__ dst,
                                int* __restrict__ cursor, int* __restrict__ esrc, int e) {
    int i = blockIdx.x * 256 + threadIdx.x;
    if (i >= e) return;
    int s = src[i], d = dst[i];
    int pos = atomicAdd(&cursor[d], 1);
    esrc[pos] = s;
}

// ---------------- GEMM: Y[n,OUTC] = act(X[n,128]) @ W[128,OUTC] ----------------
// act = identity, or BN(scale,shift)+ReLU fused on the input while staging.
// 64-row tile per block; X^T in LDS (stride 68 -> conflict-free b128 reads);
// W streamed from global (hot in L1/L2 across all blocks).

template <int OUTC>
__global__ __launch_bounds__(256) void gemm_kernel(const float* __restrict__ X,
                                                   const float* __restrict__ W,
                                                   const float* __restrict__ scale,
                                                   const float* __restrict__ shift,
                                                   float* __restrict__ Y, int n) {
    constexpr int RPT = (OUTC == 128) ? 8 : 4;  // rows per thread
    constexpr int CG  = OUTC / 4;               // col groups (float4 each)
    __shared__ float lXT[128 * 68];             // [k][row], 34.8 KB
    const int t = threadIdx.x;
    const int base = blockIdx.x * 64;
    const bool bn = (scale != nullptr);

    // stage X^T (64 rows x 128 k) with optional BN+ReLU
#pragma unroll
    for (int i = 0; i < 8; i++) {
        int id = i * 256 + t;
        int k  = id & 127;
        int r4 = id >> 7;  // 0..15
        float sc = 1.0f, sh = 0.0f;
        if (bn) { sc = scale[k]; sh = shift[k]; }
        float v[4];
#pragma unroll
        for (int j = 0; j < 4; j++) {
            int r = base + r4 * 4 + j;
            float xv = 0.0f;
            if (r < n) xv = X[(size_t)r * 128 + k];
            if (bn) xv = fmaxf(fmaf(xv, sc, sh), 0.0f);
            v[j] = xv;
        }
        float4 vv; vv.x = v[0]; vv.y = v[1]; vv.z = v[2]; vv.w = v[3];
        *(float4*)&lXT[k * 68 + r4 * 4] = vv;
    }
    __syncthreads();

    const int cg = t % CG;
    const int rg = t / CG;
    float acc[RPT][4];
#pragma unroll
    for (int i = 0; i < RPT; i++)
#pragma unroll
        for (int j = 0; j < 4; j++) acc[i][j] = 0.0f;

#pragma unroll 4
    for (int k = 0; k < 128; k++) {
        float4 b = *(const float4*)&W[k * OUTC + cg * 4];
        float a[RPT];
        *(float4*)&a[0] = *(const float4*)&lXT[k * 68 + rg * RPT];
        if constexpr (RPT == 8)
            *(float4*)&a[4] = *(const float4*)&lXT[k * 68 + rg * RPT + 4];
#pragma unroll
        for (int i = 0; i < RPT; i++) {
            acc[i][0] = fmaf(a[i], b.x, acc[i][0]);
            acc[i][1] = fmaf(a[i], b.y, acc[i][1]);
            acc[i][2] = fmaf(a[i], b.z, acc[i][2]);
            acc[i][3] = fmaf(a[i], b.w, acc[i][3]);
        }
    }

#pragma unroll
    for (int i = 0; i < RPT; i++) {
        int r = base + rg * RPT + i;
        if (r < n) {
            float4 o; o.x = acc[i][0]; o.y = acc[i][1]; o.z = acc[i][2]; o.w = acc[i][3];
            *(float4*)&Y[(size_t)r * OUTC + cg * 4] = o;
        }
    }
}

// ---------------- aggregation ----------------
// out[i] = sum_{e:dst=i} dinv[src_e]*dinv[i] * xw[src_e] + dinv[i]^2 * xw[i] + bias
// one wave per node; 8-wide edge batching keeps 8 gathers in flight per wave.

template <int COLS>
__global__ __launch_bounds__(256) void agg_kernel(const float* __restrict__ xw,
                                                  const int* __restrict__ rowptr,
                                                  const int* __restrict__ cnt,
                                                  const int* __restrict__ esrc,
                                                  const float* __restrict__ dinv,
                                                  const float* __restrict__ bias,
                                                  float* __restrict__ out, int n) {
    int gid = blockIdx.x * 256 + threadIdx.x;
    int node = gid >> 6;
    int lane = gid & 63;
    if (node >= n) return;
    float di = dinv[node];
    float sw = di * di;
    int beg = rowptr[node];
    int end = beg + cnt[node];

    if constexpr (COLS == 128) {
        float2 a = ((const float2*)(xw + (size_t)node * 128))[lane];
        float ax = sw * a.x, ay = sw * a.y;
        int e = beg;
        for (; e + 8 <= end; e += 8) {
            int s[8];
#pragma unroll
            for (int j = 0; j < 8; j++) s[j] = esrc[e + j];
            float w[8];
            float2 v[8];
#pragma unroll
            for (int j = 0; j < 8; j++) {
                w[j] = dinv[s[j]];
                v[j] = ((const float2*)(xw + (size_t)s[j] * 128))[lane];
            }
#pragma unroll
            for (int j = 0; j < 8; j++) {
                float ww = w[j] * di;
                ax = fmaf(ww, v[j].x, ax);
                ay = fmaf(ww, v[j].y, ay);
            }
        }
        for (; e < end; e++) {
            int s = esrc[e];
            float ww = dinv[s] * di;
            float2 v = ((const float2*)(xw + (size_t)s * 128))[lane];
            ax = fmaf(ww, v.x, ax);
            ay = fmaf(ww, v.y, ay);
        }
        float2 b = ((const float2*)bias)[lane];
        float2 o; o.x = ax + b.x; o.y = ay + b.y;
        ((float2*)(out + (size_t)node * 128))[lane] = o;
    } else {
        float acc = sw * xw[(size_t)node * 64 + lane];
        int e = beg;
        for (; e + 8 <= end; e += 8) {
            int s[8];
#pragma unroll
            for (int j = 0; j < 8; j++) s[j] = esrc[e + j];
            float w[8];
            float v[8];
#pragma unroll
            for (int j = 0; j < 8; j++) {
                w[j] = dinv[s[j]];
                v[j] = xw[(size_t)s[j] * 64 + lane];
            }
#pragma unroll
            for (int j = 0; j < 8; j++) acc = fmaf(w[j] * di, v[j], acc);
        }
        for (; e < end; e++) {
            int s = esrc[e];
            acc = fmaf(dinv[s] * di, xw[(size_t)s * 64 + lane], acc);
        }
        out[(size_t)node * 64 + lane] = acc + bias[lane];
    }
}

// ---------------- BatchNorm (training-mode, biased var) ----------------

__global__ void bn_stats_kernel(const float* __restrict__ h, float* __restrict__ sums, int n) {
    int c = threadIdx.x & 127;
    int half = threadIdx.x >> 7;
    float s = 0.0f, q = 0.0f;
    for (int r = blockIdx.x * 2 + half; r < n; r += gridDim.x * 2) {
        float v = h[(size_t)r * 128 + c];
        s += v;
        q = fmaf(v, v, q);
    }
    __shared__ float ls[256], lq[256];
    ls[threadIdx.x] = s; lq[threadIdx.x] = q;
    __syncthreads();
    if (half == 0) {
        s += ls[c + 128];
        q += lq[c + 128];
        atomicAdd(&sums[c], s);
        atomicAdd(&sums[128 + c], q);
    }
}

__global__ void bn_finalize_kernel(const float* __restrict__ sums, const float* __restrict__ g,
                                   const float* __restrict__ be, float* __restrict__ scale,
                                   float* __restrict__ shift, int n) {
    int c = threadIdx.x;  // 128 threads
    float inv_n = 1.0f / (float)n;
    float mean = sums[c] * inv_n;
    float var = sums[128 + c] * inv_n - mean * mean;
    float rstd = rsqrtf(var + BN_EPS);
    float sc = rstd * g[c];
    scale[c] = sc;
    shift[c] = be[c] - mean * sc;
}

// ---------------- launch ----------------

extern "C" void kernel_launch(void* const* d_in, const int* in_sizes, int n_in,
                              void* d_out, int out_size, void* d_ws, size_t ws_size,
                              hipStream_t stream) {
    const float* x   = (const float*)d_in[0];
    const int*   ei  = (const int*)d_in[1];
    const float* W1  = (const float*)d_in[2];
    const float* b1  = (const float*)d_in[3];
    const float* g1  = (const float*)d_in[4];
    const float* be1 = (const float*)d_in[5];
    const float* W2  = (const float*)d_in[6];
    const float* b2  = (const float*)d_in[7];
    const float* g2  = (const float*)d_in[8];
    const float* be2 = (const float*)d_in[9];
    const float* W3  = (const float*)d_in[10];
    const float* b3  = (const float*)d_in[11];

    const int n = in_sizes[0] / 128;
    const int E = in_sizes[1] / 2;
    const int* srcv = ei;
    const int* dstv = ei + E;

    char* p = (char*)d_ws;
    auto carve = [&](size_t bytes) -> char* {
        char* q = p;
        p += (bytes + 255) & ~(size_t)255;
        return q;
    };
    int*   cnt    = (int*)carve((size_t)n * 4);
    int*   rowptr = (int*)carve((size_t)n * 4);
    int*   cursor = (int*)carve((size_t)n * 4);
    float* dinv   = (float*)carve((size_t)n * 4);
    int*   esrc   = (int*)carve((size_t)E * 4);
    float* sums   = (float*)carve(512 * 4);   // [sum1|sq1|sum2|sq2]
    float* bnsc   = (float*)carve(512 * 4);   // [scale1|shift1|scale2|shift2]
    int*   bsum   = (int*)carve(1024 * 4);
    float* bufA   = (float*)carve((size_t)n * 128 * 4);
    float* bufB   = (float*)carve((size_t)n * 128 * 4);

    hipMemsetAsync(cnt, 0, (size_t)n * 4, stream);
    hipMemsetAsync(sums, 0, 512 * 4, stream);

    int eb = (E + 255) / 256;
    int nb = (n + 255) / 256;
    int sb = (n + 1023) / 1024;   // scan blocks (1024 elems per block); must be <= 256
    count_deg_kernel<<<eb, 256, 0, stream>>>(dstv, cnt, E);
    dinv_kernel<<<nb, 256, 0, stream>>>(cnt, dinv, n);
    blocksum_kernel<<<sb, 256, 0, stream>>>(cnt, bsum, n);
    scan_bsum_kernel<<<1, 256, 0, stream>>>(bsum, sb);
    scan_write_kernel<<<sb, 256, 0, stream>>>(cnt, bsum, rowptr, cursor, n);
    fill_csr_kernel<<<eb, 256, 0, stream>>>(srcv, dstv, cursor, esrc, E);

    int gb = (n + 63) / 64;
    int ab = (n + 3) / 4;

    // layer 1: gcn(x, W1) + b1
    gemm_kernel<128><<<gb, 256, 0, stream>>>(x, W1, nullptr, nullptr, bufA, n);
    agg_kernel<128><<<ab, 256, 0, stream>>>(bufA, rowptr, cnt, esrc, dinv, b1, bufB, n);
    bn_stats_kernel<<<512, 256, 0, stream>>>(bufB, sums, n);
    bn_finalize_kernel<<<1, 128, 0, stream>>>(sums, g1, be1, bnsc, bnsc + 128, n);

    // layer 2: gcn(relu(bn1(h)), W2) + b2   (bn1+relu fused into gemm staging)
    gemm_kernel<128><<<gb, 256, 0, stream>>>(bufB, W2, bnsc, bnsc + 128, bufA, n);
    agg_kernel<128><<<ab, 256, 0, stream>>>(bufA, rowptr, cnt, esrc, dinv, b2, bufB, n);
    bn_stats_kernel<<<512, 256, 0, stream>>>(bufB, sums + 256, n);
    bn_finalize_kernel<<<1, 128, 0, stream>>>(sums + 256, g2, be2, bnsc + 256, bnsc + 384, n);

    // layer 3: gcn(relu(bn2(h)), W3) + b3  -> d_out
    gemm_kernel<64><<<gb, 256, 0, stream>>>(bufB, W3, bnsc + 256, bnsc + 384, bufA, n);
    agg_kernel<64><<<ab, 256, 0, stream>>>(bufA, rowptr, cnt, esrc, dinv, b3, (float*)d_out, n);
}

// Round 5
// 760.997 us; speedup vs baseline: 1.4451x; 1.1124x over previous
//
#include <hip/hip_runtime.h>
#include <cstdint>
#include <cstddef>

#define BN_EPS 1e-5f

// ---- manual bf16 helpers (hip_bf16.h intrinsics unavailable in this ROCm) ----
__device__ __forceinline__ unsigned int f32_to_bf16_rne(float f) {
    unsigned int u = __float_as_uint(f);
    u += 0x7FFFu + ((u >> 16) & 1u);
    return u >> 16;
}
__device__ __forceinline__ unsigned int pack_bf16x2(float a, float b) {
    return f32_to_bf16_rne(a) | (f32_to_bf16_rne(b) << 16);
}
__device__ __forceinline__ float bf16_lo(unsigned int p) { return __uint_as_float(p << 16); }
__device__ __forceinline__ float bf16_hi(unsigned int p) { return __uint_as_float(p & 0xFFFF0000u); }

// ---------------- graph preprocessing ----------------

__global__ void count_deg_kernel(const int* __restrict__ dst, int* __restrict__ cnt, int e) {
    int i = blockIdx.x * 256 + threadIdx.x;
    if (i < e) atomicAdd(&cnt[dst[i]], 1);
}

__global__ void dinv_kernel(const int* __restrict__ cnt, float* __restrict__ dinv, int n) {
    int i = blockIdx.x * 256 + threadIdx.x;
    if (i < n) dinv[i] = rsqrtf((float)(cnt[i] + 1));   // +1 self-loop; always > 0
}

// ---- 3-phase device-wide exclusive scan: 1024 elements/block, 256 thr ----

__global__ void blocksum_kernel(const int* __restrict__ cnt, int* __restrict__ bsum, int n) {
    int t = threadIdx.x;
    int base = blockIdx.x * 1024 + t * 4;
    int s = 0;
    if (base + 3 < n) {
        int4 v = *(const int4*)&cnt[base];
        s = v.x + v.y + v.z + v.w;
    } else {
        for (int j = 0; j < 4; j++) if (base + j < n) s += cnt[base + j];
    }
    __shared__ int ls[256];
    ls[t] = s;
    __syncthreads();
    for (int off = 128; off > 0; off >>= 1) {
        if (t < off) ls[t] += ls[t + off];
        __syncthreads();
    }
    if (t == 0) bsum[blockIdx.x] = ls[0];
}

// single block, nb <= 256: exclusive scan of bsum in place
__global__ void scan_bsum_kernel(int* __restrict__ bsum, int nb) {
    int t = threadIdx.x;
    __shared__ int ls[256];
    int v = (t < nb) ? bsum[t] : 0;
    ls[t] = v;
    __syncthreads();
    for (int off = 1; off < 256; off <<= 1) {
        int p = (t >= off) ? ls[t - off] : 0;
        __syncthreads();
        ls[t] += p;
        __syncthreads();
    }
    if (t < nb) bsum[t] = ls[t] - v;   // inclusive -> exclusive
}

__global__ void scan_write_kernel(const int* __restrict__ cnt, const int* __restrict__ bsum,
                                  int* __restrict__ rowptr, int* __restrict__ cursor, int n) {
    int t = threadIdx.x;
    int base = blockIdx.x * 1024 + t * 4;
    int v[4];
    int s = 0;
    if (base + 3 < n) {
        int4 q = *(const int4*)&cnt[base];
        v[0] = q.x; v[1] = q.y; v[2] = q.z; v[3] = q.w;
        s = q.x + q.y + q.z + q.w;
    } else {
        for (int j = 0; j < 4; j++) { v[j] = (base + j < n) ? cnt[base + j] : 0; s += v[j]; }
    }
    __shared__ int ls[256];
    ls[t] = s;
    __syncthreads();
    for (int off = 1; off < 256; off <<= 1) {
        int p = (t >= off) ? ls[t - off] : 0;
        __syncthreads();
        ls[t] += p;
        __syncthreads();
    }
    int run = bsum[blockIdx.x] + ls[t] - s;   // exclusive offset for this thread
    if (base + 3 < n) {
        int4 r; r.x = run; r.y = run + v[0]; r.z = run + v[0] + v[1]; r.w = run + v[0] + v[1] + v[2];
        *(int4*)&rowptr[base] = r;
        *(int4*)&cursor[base] = r;
    } else {
        for (int j = 0; j < 4; j++) {
            if (base + j < n) { rowptr[base + j] = run; cursor[base + j] = run; }
            run += v[j];
        }
    }
}

// CSR fill: ONLY the src index is scattered (4B/edge); norm recomputed in agg.
__global__ void fill_csr_kernel(const int* __restrict__ src, const int* __restrict__ dst,
                                int* __restrict__ cursor, int* __restrict__ esrc, int e) {
    int i = blockIdx.x * 256 + threadIdx.x;
    if (i >= e) return;
    int s = src[i], d = dst[i];
    int pos = atomicAdd(&cursor[d], 1);
    esrc[pos] = s;
}

// ---------------- GEMM: Y[n,OUTC](bf16) = act(X[n,128]) @ W[128,OUTC] ----------------
// act = identity, or BN(scale,shift)+ReLU fused on the input while staging.
// Output stored bf16 (only consumed by the gather-heavy agg kernel).

template <int OUTC>
__global__ __launch_bounds__(256) void gemm_kernel(const float* __restrict__ X,
                                                   const float* __restrict__ W,
                                                   const float* __restrict__ scale,
                                                   const float* __restrict__ shift,
                                                   unsigned int* __restrict__ Y, int n) {
    constexpr int RPT = (OUTC == 128) ? 8 : 4;  // rows per thread
    constexpr int CG  = OUTC / 4;               // col groups (4 cols each)
    __shared__ float lXT[128 * 68];             // [k][row], 34.8 KB
    const int t = threadIdx.x;
    const int base = blockIdx.x * 64;
    const bool bn = (scale != nullptr);

    // stage X^T (64 rows x 128 k) with optional BN+ReLU
#pragma unroll
    for (int i = 0; i < 8; i++) {
        int id = i * 256 + t;
        int k  = id & 127;
        int r4 = id >> 7;  // 0..15
        float sc = 1.0f, sh = 0.0f;
        if (bn) { sc = scale[k]; sh = shift[k]; }
        float v[4];
#pragma unroll
        for (int j = 0; j < 4; j++) {
            int r = base + r4 * 4 + j;
            float xv = 0.0f;
            if (r < n) xv = X[(size_t)r * 128 + k];
            if (bn) xv = fmaxf(fmaf(xv, sc, sh), 0.0f);
            v[j] = xv;
        }
        float4 vv; vv.x = v[0]; vv.y = v[1]; vv.z = v[2]; vv.w = v[3];
        *(float4*)&lXT[k * 68 + r4 * 4] = vv;
    }
    __syncthreads();

    const int cg = t % CG;
    const int rg = t / CG;
    float acc[RPT][4];
#pragma unroll
    for (int i = 0; i < RPT; i++)
#pragma unroll
        for (int j = 0; j < 4; j++) acc[i][j] = 0.0f;

#pragma unroll 4
    for (int k = 0; k < 128; k++) {
        float4 b = *(const float4*)&W[k * OUTC + cg * 4];
        float a[RPT];
        *(float4*)&a[0] = *(const float4*)&lXT[k * 68 + rg * RPT];
        if constexpr (RPT == 8)
            *(float4*)&a[4] = *(const float4*)&lXT[k * 68 + rg * RPT + 4];
#pragma unroll
        for (int i = 0; i < RPT; i++) {
            acc[i][0] = fmaf(a[i], b.x, acc[i][0]);
            acc[i][1] = fmaf(a[i], b.y, acc[i][1]);
            acc[i][2] = fmaf(a[i], b.z, acc[i][2]);
            acc[i][3] = fmaf(a[i], b.w, acc[i][3]);
        }
    }

    // Y layout: row-major bf16, i.e. OUTC/2 uints per row; this thread owns
    // uint pair indices [cg*2, cg*2+1] of each of its RPT rows.
#pragma unroll
    for (int i = 0; i < RPT; i++) {
        int r = base + rg * RPT + i;
        if (r < n) {
            uint2 o;
            o.x = pack_bf16x2(acc[i][0], acc[i][1]);
            o.y = pack_bf16x2(acc[i][2], acc[i][3]);
            *(uint2*)&Y[(size_t)r * (OUTC / 2) + cg * 2] = o;
        }
    }
}

// ---------------- aggregation ----------------
// out[i] = sum_{e:dst=i} dinv[src_e]*dinv[i] * xw[src_e] + dinv[i]^2 * xw[i] + bias
// xw is bf16 packed in uints (halves gather bytes); accumulate fp32;
// one wave per node; 8-wide edge batching keeps 8 gathers in flight per wave.

template <int COLS>
__global__ __launch_bounds__(256) void agg_kernel(const unsigned int* __restrict__ xw,
                                                  const int* __restrict__ rowptr,
                                                  const int* __restrict__ cnt,
                                                  const int* __restrict__ esrc,
                                                  const float* __restrict__ dinv,
                                                  const float* __restrict__ bias,
                                                  float* __restrict__ out, int n) {
    int gid = blockIdx.x * 256 + threadIdx.x;
    int node = gid >> 6;
    int lane = gid & 63;
    if (node >= n) return;
    float di = dinv[node];
    float sw = di * di;
    int beg = rowptr[node];
    int end = beg + cnt[node];

    if constexpr (COLS == 128) {
        // 64 uints per row; lane i owns uint i (cols 2i, 2i+1)
        unsigned int ap = xw[(size_t)node * 64 + lane];
        float ax = sw * bf16_lo(ap), ay = sw * bf16_hi(ap);
        int e = beg;
        for (; e + 8 <= end; e += 8) {
            int s[8];
#pragma unroll
            for (int j = 0; j < 8; j++) s[j] = esrc[e + j];
            float w[8];
            unsigned int v[8];
#pragma unroll
            for (int j = 0; j < 8; j++) {
                w[j] = dinv[s[j]];
                v[j] = xw[(size_t)s[j] * 64 + lane];
            }
#pragma unroll
            for (int j = 0; j < 8; j++) {
                float ww = w[j] * di;
                ax = fmaf(ww, bf16_lo(v[j]), ax);
                ay = fmaf(ww, bf16_hi(v[j]), ay);
            }
        }
        for (; e < end; e++) {
            int s = esrc[e];
            float ww = dinv[s] * di;
            unsigned int v = xw[(size_t)s * 64 + lane];
            ax = fmaf(ww, bf16_lo(v), ax);
            ay = fmaf(ww, bf16_hi(v), ay);
        }
        float2 b = ((const float2*)bias)[lane];
        float2 o; o.x = ax + b.x; o.y = ay + b.y;
        ((float2*)(out + (size_t)node * 128))[lane] = o;
    } else {
        // 32 uints per row; lanes 0..31 own uint lane (cols 2l, 2l+1); lanes 32+ idle on loads
        // -> instead: each lane handles ONE bf16 column via 16-bit extract from uint lane>>1.
        unsigned int ap = xw[(size_t)node * 32 + (lane >> 1)];
        float a0 = (lane & 1) ? bf16_hi(ap) : bf16_lo(ap);
        float acc = sw * a0;
        int e = beg;
        for (; e + 8 <= end; e += 8) {
            int s[8];
#pragma unroll
            for (int j = 0; j < 8; j++) s[j] = esrc[e + j];
            float w[8];
            unsigned int v[8];
#pragma unroll
            for (int j = 0; j < 8; j++) {
                w[j] = dinv[s[j]];
                v[j] = xw[(size_t)s[j] * 32 + (lane >> 1)];
            }
#pragma unroll
            for (int j = 0; j < 8; j++) {
                float vf = (lane & 1) ? bf16_hi(v[j]) : bf16_lo(v[j]);
                acc = fmaf(w[j] * di, vf, acc);
            }
        }
        for (; e < end; e++) {
            int s = esrc[e];
            unsigned int v = xw[(size_t)s * 32 + (lane >> 1)];
            float vf = (lane & 1) ? bf16_hi(v) : bf16_lo(v);
            acc = fmaf(dinv[s] * di, vf, acc);
        }
        out[(size_t)node * 64 + lane] = acc + bias[lane];
    }
}

// ---------------- BatchNorm (training-mode, biased var) ----------------

__global__ void bn_stats_kernel(const float* __restrict__ h, float* __restrict__ sums, int n) {
    int c = threadIdx.x & 127;
    int half = threadIdx.x >> 7;
    float s = 0.0f, q = 0.0f;
    for (int r = blockIdx.x * 2 + half; r < n; r += gridDim.x * 2) {
        float v = h[(size_t)r * 128 + c];
        s += v;
        q = fmaf(v, v, q);
    }
    __shared__ float ls[256], lq[256];
    ls[threadIdx.x] = s; lq[threadIdx.x] = q;
    __syncthreads();
    if (half == 0) {
        s += ls[c + 128];
        q += lq[c + 128];
        atomicAdd(&sums[c], s);
        atomicAdd(&sums[128 + c], q);
    }
}

__global__ void bn_finalize_kernel(const float* __restrict__ sums, const float* __restrict__ g,
                                   const float* __restrict__ be, float* __restrict__ scale,
                                   float* __restrict__ shift, int n) {
    int c = threadIdx.x;  // 128 threads
    float inv_n = 1.0f / (float)n;
    float mean = sums[c] * inv_n;
    float var = sums[128 + c] * inv_n - mean * mean;
    float rstd = rsqrtf(var + BN_EPS);
    float sc = rstd * g[c];
    scale[c] = sc;
    shift[c] = be[c] - mean * sc;
}

// ---------------- launch ----------------

extern "C" void kernel_launch(void* const* d_in, const int* in_sizes, int n_in,
                              void* d_out, int out_size, void* d_ws, size_t ws_size,
                              hipStream_t stream) {
    const float* x   = (const float*)d_in[0];
    const int*   ei  = (const int*)d_in[1];
    const float* W1  = (const float*)d_in[2];
    const float* b1  = (const float*)d_in[3];
    const float* g1  = (const float*)d_in[4];
    const float* be1 = (const float*)d_in[5];
    const float* W2  = (const float*)d_in[6];
    const float* b2  = (const float*)d_in[7];
    const float* g2  = (const float*)d_in[8];
    const float* be2 = (const float*)d_in[9];
    const float* W3  = (const float*)d_in[10];
    const float* b3  = (const float*)d_in[11];

    const int n = in_sizes[0] / 128;
    const int E = in_sizes[1] / 2;
    const int* srcv = ei;
    const int* dstv = ei + E;

    char* p = (char*)d_ws;
    auto carve = [&](size_t bytes) -> char* {
        char* q = p;
        p += (bytes + 255) & ~(size_t)255;
        return q;
    };
    int*   cnt    = (int*)carve((size_t)n * 4);
    int*   rowptr = (int*)carve((size_t)n * 4);
    int*   cursor = (int*)carve((size_t)n * 4);
    float* dinv   = (float*)carve((size_t)n * 4);
    int*   esrc   = (int*)carve((size_t)E * 4);
    float* sums   = (float*)carve(512 * 4);   // [sum1|sq1|sum2|sq2]
    float* bnsc   = (float*)carve(512 * 4);   // [scale1|shift1|scale2|shift2]
    int*   bsum   = (int*)carve(1024 * 4);
    unsigned int* xwb = (unsigned int*)carve((size_t)n * 128 * 2);  // gemm out (bf16 packed)
    float* bufB   = (float*)carve((size_t)n * 128 * 4);             // agg out (fp32)

    hipMemsetAsync(cnt, 0, (size_t)n * 4, stream);
    hipMemsetAsync(sums, 0, 512 * 4, stream);

    int eb = (E + 255) / 256;
    int nb = (n + 255) / 256;
    int sb = (n + 1023) / 1024;   // scan blocks (1024 elems per block); must be <= 256
    count_deg_kernel<<<eb, 256, 0, stream>>>(dstv, cnt, E);
    dinv_kernel<<<nb, 256, 0, stream>>>(cnt, dinv, n);
    blocksum_kernel<<<sb, 256, 0, stream>>>(cnt, bsum, n);
    scan_bsum_kernel<<<1, 256, 0, stream>>>(bsum, sb);
    scan_write_kernel<<<sb, 256, 0, stream>>>(cnt, bsum, rowptr, cursor, n);
    fill_csr_kernel<<<eb, 256, 0, stream>>>(srcv, dstv, cursor, esrc, E);

    int gb = (n + 63) / 64;
    int ab = (n + 3) / 4;

    // layer 1: gcn(x, W1) + b1
    gemm_kernel<128><<<gb, 256, 0, stream>>>(x, W1, nullptr, nullptr, xwb, n);
    agg_kernel<128><<<ab, 256, 0, stream>>>(xwb, rowptr, cnt, esrc, dinv, b1, bufB, n);
    bn_stats_kernel<<<512, 256, 0, stream>>>(bufB, sums, n);
    bn_finalize_kernel<<<1, 128, 0, stream>>>(sums, g1, be1, bnsc, bnsc + 128, n);

    // layer 2: gcn(relu(bn1(h)), W2) + b2   (bn1+relu fused into gemm staging)
    gemm_kernel<128><<<gb, 256, 0, stream>>>(bufB, W2, bnsc, bnsc + 128, xwb, n);
    agg_kernel<128><<<ab, 256, 0, stream>>>(xwb, rowptr, cnt, esrc, dinv, b2, bufB, n);
    bn_stats_kernel<<<512, 256, 0, stream>>>(bufB, sums + 256, n);
    bn_finalize_kernel<<<1, 128, 0, stream>>>(sums + 256, g2, be2, bnsc + 256, bnsc + 384, n);

    // layer 3: gcn(relu(bn2(h)), W3) + b3  -> d_out
    gemm_kernel<64><<<gb, 256, 0, stream>>>(bufB, W3, bnsc + 256, bnsc + 384, xwb, n);
    agg_kernel<64><<<ab, 256, 0, stream>>>(xwb, rowptr, cnt, esrc, dinv, b3, (float*)d_out, n);
}

// Round 6
// 700.588 us; speedup vs baseline: 1.5697x; 1.0862x over previous
//
#include <hip/hip_runtime.h>
#include <cstdint>
#include <cstddef>

#define BN_EPS 1e-5f
#define BK 64          // buckets (dst>>11); 100000>>11 = 48 -> 49 used
#define BSH 11
#define CHUNK 4096     // edges per block in hist/scatter

// ---- manual bf16 helpers (hip_bf16.h intrinsics unavailable in this ROCm) ----
__device__ __forceinline__ unsigned int f32_to_bf16_rne(float f) {
    unsigned int u = __float_as_uint(f);
    u += 0x7FFFu + ((u >> 16) & 1u);
    return u >> 16;
}
__device__ __forceinline__ unsigned int pack_bf16x2(float a, float b) {
    return f32_to_bf16_rne(a) | (f32_to_bf16_rne(b) << 16);
}
__device__ __forceinline__ float bf16_lo(unsigned int p) { return __uint_as_float(p << 16); }
__device__ __forceinline__ float bf16_hi(unsigned int p) { return __uint_as_float(p & 0xFFFF0000u); }

// ---------------- bucketed CSR build ----------------
// Phase 1: per-(bucket,block) histogram H[b*G+g]
__global__ void hist64_kernel(const int* __restrict__ dst, int* __restrict__ H, int e, int G) {
    __shared__ int h[BK];
    int t = threadIdx.x, g = blockIdx.x;
    if (t < BK) h[t] = 0;
    __syncthreads();
    int base = g * CHUNK;
#pragma unroll
    for (int i = 0; i < CHUNK / 256; i++) {
        int idx = base + i * 256 + t;
        if (idx < e) atomicAdd(&h[dst[idx] >> BSH], 1);
    }
    __syncthreads();
    if (t < BK) H[t * G + g] = h[t];
}

// Phase 3: scatter (src,dst) into bucket-contiguous binned array.
__global__ void bin_scatter_kernel(const int* __restrict__ src, const int* __restrict__ dst,
                                   const int* __restrict__ Hscan, uint2* __restrict__ binned,
                                   int e, int G) {
    __shared__ int cur[BK];
    int t = threadIdx.x, g = blockIdx.x;
    if (t < BK) cur[t] = Hscan[t * G + g];
    __syncthreads();
    int base = g * CHUNK;
#pragma unroll
    for (int i = 0; i < CHUNK / 256; i++) {
        int idx = base + i * 256 + t;
        if (idx < e) {
            int s = src[idx], d = dst[idx];
            int pos = atomicAdd(&cur[d >> BSH], 1);
            uint2 v; v.x = (unsigned)s; v.y = (unsigned)d;
            binned[pos] = v;
        }
    }
}

// Per-bucket degree count with XCD affinity (bucket = blockIdx % 64 -> XCD b%8).
__global__ void count_deg_binned_kernel(const uint2* __restrict__ binned,
                                        const int* __restrict__ Hscan,
                                        int* __restrict__ cnt, int e, int G, int P) {
    int b = blockIdx.x & (BK - 1);
    int p = blockIdx.x >> 6;
    int s = Hscan[b * G];
    int en = (b < BK - 1) ? Hscan[(b + 1) * G] : e;
    long long len = en - s;
    int c0 = s + (int)(len * p / P);
    int c1 = s + (int)(len * (p + 1) / P);
    for (int i = c0 + threadIdx.x; i < c1; i += 256)
        atomicAdd(&cnt[binned[i].y], 1);
}

// Per-bucket CSR fill (atomic cursor + scattered store stay XCD-local).
__global__ void fill_binned_kernel(const uint2* __restrict__ binned,
                                   const int* __restrict__ Hscan,
                                   int* __restrict__ cursor, int* __restrict__ esrc,
                                   int e, int G, int P) {
    int b = blockIdx.x & (BK - 1);
    int p = blockIdx.x >> 6;
    int s = Hscan[b * G];
    int en = (b < BK - 1) ? Hscan[(b + 1) * G] : e;
    long long len = en - s;
    int c0 = s + (int)(len * p / P);
    int c1 = s + (int)(len * (p + 1) / P);
    for (int i = c0 + threadIdx.x; i < c1; i += 256) {
        uint2 ed = binned[i];
        int pos = atomicAdd(&cursor[ed.y], 1);
        esrc[pos] = (int)ed.x;
    }
}

__global__ void dinv_kernel(const int* __restrict__ cnt, float* __restrict__ dinv, int n) {
    int i = blockIdx.x * 256 + threadIdx.x;
    if (i < n) dinv[i] = rsqrtf((float)(cnt[i] + 1));   // +1 self-loop; always > 0
}

// ---- 3-phase device-wide exclusive scan: 1024 elements/block, 256 thr ----

__global__ void blocksum_kernel(const int* __restrict__ cnt, int* __restrict__ bsum, int n) {
    int t = threadIdx.x;
    int base = blockIdx.x * 1024 + t * 4;
    int s = 0;
    if (base + 3 < n) {
        int4 v = *(const int4*)&cnt[base];
        s = v.x + v.y + v.z + v.w;
    } else {
        for (int j = 0; j < 4; j++) if (base + j < n) s += cnt[base + j];
    }
    __shared__ int ls[256];
    ls[t] = s;
    __syncthreads();
    for (int off = 128; off > 0; off >>= 1) {
        if (t < off) ls[t] += ls[t + off];
        __syncthreads();
    }
    if (t == 0) bsum[blockIdx.x] = ls[0];
}

// single block, nb <= 256: exclusive scan of bsum in place
__global__ void scan_bsum_kernel(int* __restrict__ bsum, int nb) {
    int t = threadIdx.x;
    __shared__ int ls[256];
    int v = (t < nb) ? bsum[t] : 0;
    ls[t] = v;
    __syncthreads();
    for (int off = 1; off < 256; off <<= 1) {
        int p = (t >= off) ? ls[t - off] : 0;
        __syncthreads();
        ls[t] += p;
        __syncthreads();
    }
    if (t < nb) bsum[t] = ls[t] - v;   // inclusive -> exclusive
}

// generic: write exclusive scan to single output array
__global__ void scan_write1_kernel(const int* __restrict__ in, const int* __restrict__ bsum,
                                   int* __restrict__ out, int n) {
    int t = threadIdx.x;
    int base = blockIdx.x * 1024 + t * 4;
    int v[4];
    int s = 0;
    if (base + 3 < n) {
        int4 q = *(const int4*)&in[base];
        v[0] = q.x; v[1] = q.y; v[2] = q.z; v[3] = q.w;
        s = q.x + q.y + q.z + q.w;
    } else {
        for (int j = 0; j < 4; j++) { v[j] = (base + j < n) ? in[base + j] : 0; s += v[j]; }
    }
    __shared__ int ls[256];
    ls[t] = s;
    __syncthreads();
    for (int off = 1; off < 256; off <<= 1) {
        int p = (t >= off) ? ls[t - off] : 0;
        __syncthreads();
        ls[t] += p;
        __syncthreads();
    }
    int run = bsum[blockIdx.x] + ls[t] - s;
    if (base + 3 < n) {
        int4 r; r.x = run; r.y = run + v[0]; r.z = run + v[0] + v[1]; r.w = run + v[0] + v[1] + v[2];
        *(int4*)&out[base] = r;
    } else {
        for (int j = 0; j < 4; j++) {
            if (base + j < n) out[base + j] = run;
            run += v[j];
        }
    }
}

// variant writing rowptr + cursor copies
__global__ void scan_write_kernel(const int* __restrict__ cnt, const int* __restrict__ bsum,
                                  int* __restrict__ rowptr, int* __restrict__ cursor, int n) {
    int t = threadIdx.x;
    int base = blockIdx.x * 1024 + t * 4;
    int v[4];
    int s = 0;
    if (base + 3 < n) {
        int4 q = *(const int4*)&cnt[base];
        v[0] = q.x; v[1] = q.y; v[2] = q.z; v[3] = q.w;
        s = q.x + q.y + q.z + q.w;
    } else {
        for (int j = 0; j < 4; j++) { v[j] = (base + j < n) ? cnt[base + j] : 0; s += v[j]; }
    }
    __shared__ int ls[256];
    ls[t] = s;
    __syncthreads();
    for (int off = 1; off < 256; off <<= 1) {
        int p = (t >= off) ? ls[t - off] : 0;
        __syncthreads();
        ls[t] += p;
        __syncthreads();
    }
    int run = bsum[blockIdx.x] + ls[t] - s;
    if (base + 3 < n) {
        int4 r; r.x = run; r.y = run + v[0]; r.z = run + v[0] + v[1]; r.w = run + v[0] + v[1] + v[2];
        *(int4*)&rowptr[base] = r;
        *(int4*)&cursor[base] = r;
    } else {
        for (int j = 0; j < 4; j++) {
            if (base + j < n) { rowptr[base + j] = run; cursor[base + j] = run; }
            run += v[j];
        }
    }
}

// ---------------- GEMM: Y[n,OUTC](bf16) = act(X[n,128]) @ W[128,OUTC] ----------------

template <int OUTC>
__global__ __launch_bounds__(256) void gemm_kernel(const float* __restrict__ X,
                                                   const float* __restrict__ W,
                                                   const float* __restrict__ scale,
                                                   const float* __restrict__ shift,
                                                   unsigned int* __restrict__ Y, int n) {
    constexpr int RPT = (OUTC == 128) ? 8 : 4;  // rows per thread
    constexpr int CG  = OUTC / 4;               // col groups (4 cols each)
    __shared__ float lXT[128 * 68];             // [k][row], 34.8 KB
    const int t = threadIdx.x;
    const int base = blockIdx.x * 64;
    const bool bn = (scale != nullptr);

#pragma unroll
    for (int i = 0; i < 8; i++) {
        int id = i * 256 + t;
        int k  = id & 127;
        int r4 = id >> 7;  // 0..15
        float sc = 1.0f, sh = 0.0f;
        if (bn) { sc = scale[k]; sh = shift[k]; }
        float v[4];
#pragma unroll
        for (int j = 0; j < 4; j++) {
            int r = base + r4 * 4 + j;
            float xv = 0.0f;
            if (r < n) xv = X[(size_t)r * 128 + k];
            if (bn) xv = fmaxf(fmaf(xv, sc, sh), 0.0f);
            v[j] = xv;
        }
        float4 vv; vv.x = v[0]; vv.y = v[1]; vv.z = v[2]; vv.w = v[3];
        *(float4*)&lXT[k * 68 + r4 * 4] = vv;
    }
    __syncthreads();

    const int cg = t % CG;
    const int rg = t / CG;
    float acc[RPT][4];
#pragma unroll
    for (int i = 0; i < RPT; i++)
#pragma unroll
        for (int j = 0; j < 4; j++) acc[i][j] = 0.0f;

#pragma unroll 4
    for (int k = 0; k < 128; k++) {
        float4 b = *(const float4*)&W[k * OUTC + cg * 4];
        float a[RPT];
        *(float4*)&a[0] = *(const float4*)&lXT[k * 68 + rg * RPT];
        if constexpr (RPT == 8)
            *(float4*)&a[4] = *(const float4*)&lXT[k * 68 + rg * RPT + 4];
#pragma unroll
        for (int i = 0; i < RPT; i++) {
            acc[i][0] = fmaf(a[i], b.x, acc[i][0]);
            acc[i][1] = fmaf(a[i], b.y, acc[i][1]);
            acc[i][2] = fmaf(a[i], b.z, acc[i][2]);
            acc[i][3] = fmaf(a[i], b.w, acc[i][3]);
        }
    }

#pragma unroll
    for (int i = 0; i < RPT; i++) {
        int r = base + rg * RPT + i;
        if (r < n) {
            uint2 o;
            o.x = pack_bf16x2(acc[i][0], acc[i][1]);
            o.y = pack_bf16x2(acc[i][2], acc[i][3]);
            *(uint2*)&Y[(size_t)r * (OUTC / 2) + cg * 2] = o;
        }
    }
}

// ---------------- aggregation ----------------

template <int COLS>
__global__ __launch_bounds__(256) void agg_kernel(const unsigned int* __restrict__ xw,
                                                  const int* __restrict__ rowptr,
                                                  const int* __restrict__ cnt,
                                                  const int* __restrict__ esrc,
                                                  const float* __restrict__ dinv,
                                                  const float* __restrict__ bias,
                                                  float* __restrict__ out, int n) {
    int gid = blockIdx.x * 256 + threadIdx.x;
    int node = gid >> 6;
    int lane = gid & 63;
    if (node >= n) return;
    float di = dinv[node];
    float sw = di * di;
    int beg = rowptr[node];
    int end = beg + cnt[node];

    if constexpr (COLS == 128) {
        unsigned int ap = xw[(size_t)node * 64 + lane];
        float ax = sw * bf16_lo(ap), ay = sw * bf16_hi(ap);
        int e = beg;
        for (; e + 8 <= end; e += 8) {
            int s[8];
#pragma unroll
            for (int j = 0; j < 8; j++) s[j] = esrc[e + j];
            float w[8];
            unsigned int v[8];
#pragma unroll
            for (int j = 0; j < 8; j++) {
                w[j] = dinv[s[j]];
                v[j] = xw[(size_t)s[j] * 64 + lane];
            }
#pragma unroll
            for (int j = 0; j < 8; j++) {
                float ww = w[j] * di;
                ax = fmaf(ww, bf16_lo(v[j]), ax);
                ay = fmaf(ww, bf16_hi(v[j]), ay);
            }
        }
        for (; e < end; e++) {
            int s = esrc[e];
            float ww = dinv[s] * di;
            unsigned int v = xw[(size_t)s * 64 + lane];
            ax = fmaf(ww, bf16_lo(v), ax);
            ay = fmaf(ww, bf16_hi(v), ay);
        }
        float2 b = ((const float2*)bias)[lane];
        float2 o; o.x = ax + b.x; o.y = ay + b.y;
        ((float2*)(out + (size_t)node * 128))[lane] = o;
    } else {
        unsigned int ap = xw[(size_t)node * 32 + (lane >> 1)];
        float a0 = (lane & 1) ? bf16_hi(ap) : bf16_lo(ap);
        float acc = sw * a0;
        int e = beg;
        for (; e + 8 <= end; e += 8) {
            int s[8];
#pragma unroll
            for (int j = 0; j < 8; j++) s[j] = esrc[e + j];
            float w[8];
            unsigned int v[8];
#pragma unroll
            for (int j = 0; j < 8; j++) {
                w[j] = dinv[s[j]];
                v[j] = xw[(size_t)s[j] * 32 + (lane >> 1)];
            }
#pragma unroll
            for (int j = 0; j < 8; j++) {
                float vf = (lane & 1) ? bf16_hi(v[j]) : bf16_lo(v[j]);
                acc = fmaf(w[j] * di, vf, acc);
            }
        }
        for (; e < end; e++) {
            int s = esrc[e];
            unsigned int v = xw[(size_t)s * 32 + (lane >> 1)];
            float vf = (lane & 1) ? bf16_hi(v) : bf16_lo(v);
            acc = fmaf(dinv[s] * di, vf, acc);
        }
        out[(size_t)node * 64 + lane] = acc + bias[lane];
    }
}

// ---------------- BatchNorm (training-mode, biased var) ----------------

__global__ void bn_stats_kernel(const float* __restrict__ h, float* __restrict__ sums, int n) {
    int c = threadIdx.x & 127;
    int half = threadIdx.x >> 7;
    float s = 0.0f, q = 0.0f;
    for (int r = blockIdx.x * 2 + half; r < n; r += gridDim.x * 2) {
        float v = h[(size_t)r * 128 + c];
        s += v;
        q = fmaf(v, v, q);
    }
    __shared__ float ls[256], lq[256];
    ls[threadIdx.x] = s; lq[threadIdx.x] = q;
    __syncthreads();
    if (half == 0) {
        s += ls[c + 128];
        q += lq[c + 128];
        atomicAdd(&sums[c], s);
        atomicAdd(&sums[128 + c], q);
    }
}

__global__ void bn_finalize_kernel(const float* __restrict__ sums, const float* __restrict__ g,
                                   const float* __restrict__ be, float* __restrict__ scale,
                                   float* __restrict__ shift, int n) {
    int c = threadIdx.x;  // 128 threads
    float inv_n = 1.0f / (float)n;
    float mean = sums[c] * inv_n;
    float var = sums[128 + c] * inv_n - mean * mean;
    float rstd = rsqrtf(var + BN_EPS);
    float sc = rstd * g[c];
    scale[c] = sc;
    shift[c] = be[c] - mean * sc;
}

// ---------------- launch ----------------

extern "C" void kernel_launch(void* const* d_in, const int* in_sizes, int n_in,
                              void* d_out, int out_size, void* d_ws, size_t ws_size,
                              hipStream_t stream) {
    const float* x   = (const float*)d_in[0];
    const int*   ei  = (const int*)d_in[1];
    const float* W1  = (const float*)d_in[2];
    const float* b1  = (const float*)d_in[3];
    const float* g1  = (const float*)d_in[4];
    const float* be1 = (const float*)d_in[5];
    const float* W2  = (const float*)d_in[6];
    const float* b2  = (const float*)d_in[7];
    const float* g2  = (const float*)d_in[8];
    const float* be2 = (const float*)d_in[9];
    const float* W3  = (const float*)d_in[10];
    const float* b3  = (const float*)d_in[11];

    const int n = in_sizes[0] / 128;
    const int E = in_sizes[1] / 2;
    const int* srcv = ei;
    const int* dstv = ei + E;

    const int G = (E + CHUNK - 1) / CHUNK;      // hist/scatter blocks (391)
    const int HN = BK * G;                       // H matrix elements (25024)

    char* p = (char*)d_ws;
    auto carve = [&](size_t bytes) -> char* {
        char* q = p;
        p += (bytes + 255) & ~(size_t)255;
        return q;
    };
    int*   cnt    = (int*)carve((size_t)n * 4);
    int*   rowptr = (int*)carve((size_t)n * 4);
    int*   cursor = (int*)carve((size_t)n * 4);
    float* dinv   = (float*)carve((size_t)n * 4);
    int*   esrc   = (int*)carve((size_t)E * 4);
    uint2* binned = (uint2*)carve((size_t)E * 8);
    int*   H      = (int*)carve((size_t)HN * 4);
    int*   Hscan  = (int*)carve((size_t)HN * 4);
    float* sums   = (float*)carve(512 * 4);   // [sum1|sq1|sum2|sq2]
    float* bnsc   = (float*)carve(512 * 4);   // [scale1|shift1|scale2|shift2]
    int*   bsum   = (int*)carve(1024 * 4);
    unsigned int* xwb = (unsigned int*)carve((size_t)n * 128 * 2);  // gemm out (bf16 packed)
    float* bufB   = (float*)carve((size_t)n * 128 * 4);             // agg out (fp32)

    hipMemsetAsync(cnt, 0, (size_t)n * 4, stream);
    hipMemsetAsync(sums, 0, 512 * 4, stream);

    int nb  = (n + 255) / 256;
    int sbH = (HN + 1023) / 1024;    // 25
    int sbN = (n + 1023) / 1024;     // 98
    const int P = 16;                // blocks per bucket in binned kernels

    // bucketed CSR build
    hist64_kernel<<<G, 256, 0, stream>>>(dstv, H, E, G);
    blocksum_kernel<<<sbH, 256, 0, stream>>>(H, bsum, HN);
    scan_bsum_kernel<<<1, 256, 0, stream>>>(bsum, sbH);
    scan_write1_kernel<<<sbH, 256, 0, stream>>>(H, bsum, Hscan, HN);
    bin_scatter_kernel<<<G, 256, 0, stream>>>(srcv, dstv, Hscan, binned, E, G);
    count_deg_binned_kernel<<<BK * P, 256, 0, stream>>>(binned, Hscan, cnt, E, G, P);
    dinv_kernel<<<nb, 256, 0, stream>>>(cnt, dinv, n);
    blocksum_kernel<<<sbN, 256, 0, stream>>>(cnt, bsum, n);
    scan_bsum_kernel<<<1, 256, 0, stream>>>(bsum, sbN);
    scan_write_kernel<<<sbN, 256, 0, stream>>>(cnt, bsum, rowptr, cursor, n);
    fill_binned_kernel<<<BK * P, 256, 0, stream>>>(binned, Hscan, cursor, esrc, E, G, P);

    int gb = (n + 63) / 64;
    int ab = (n + 3) / 4;

    // layer 1: gcn(x, W1) + b1
    gemm_kernel<128><<<gb, 256, 0, stream>>>(x, W1, nullptr, nullptr, xwb, n);
    agg_kernel<128><<<ab, 256, 0, stream>>>(xwb, rowptr, cnt, esrc, dinv, b1, bufB, n);
    bn_stats_kernel<<<512, 256, 0, stream>>>(bufB, sums, n);
    bn_finalize_kernel<<<1, 128, 0, stream>>>(sums, g1, be1, bnsc, bnsc + 128, n);

    // layer 2: gcn(relu(bn1(h)), W2) + b2   (bn1+relu fused into gemm staging)
    gemm_kernel<128><<<gb, 256, 0, stream>>>(bufB, W2, bnsc, bnsc + 128, xwb, n);
    agg_kernel<128><<<ab, 256, 0, stream>>>(xwb, rowptr, cnt, esrc, dinv, b2, bufB, n);
    bn_stats_kernel<<<512, 256, 0, stream>>>(bufB, sums + 256, n);
    bn_finalize_kernel<<<1, 128, 0, stream>>>(sums + 256, g2, be2, bnsc + 256, bnsc + 384, n);

    // layer 3: gcn(relu(bn2(h)), W3) + b3  -> d_out
    gemm_kernel<64><<<gb, 256, 0, stream>>>(bufB, W3, bnsc + 256, bnsc + 384, xwb, n);
    agg_kernel<64><<<ab, 256, 0, stream>>>(xwb, rowptr, cnt, esrc, dinv, b3, (float*)d_out, n);
}